// Round 2
// baseline (652.110 us; speedup 1.0000x reference)
//
#include <hip/hip_runtime.h>
#include <stdint.h>

#define NN 100000
#define EE 1600000
#define FD 128

// ---------------------------------------------------------------------------
// threefry2x32 (Random123 / JAX standard 20-round). Reproduces
// jax.random.bernoulli masks bit-exactly in threefry_partitionable mode
// (JAX >= 0.4.36 default):
//   split(key)[i]        = (x0, x1) of block with counter (0, i)
//   random_bits32 elem m = x0 ^ x1 of block with counter (0, m)   [R2 FIX]
// R1 used x1-only for random_bits -> absmax stuck at 4.2e-2 (mask-wrong
// signature). If STILL ~4e-2: harness JAX is non-partitionable -> original
// scheme: m < size/2 ? x0 of (m, m+size/2) : x1 of (m-size/2, m); split
// children from blocks (0,2),(1,3).
// ---------------------------------------------------------------------------
struct TF2 { uint32_t x0, x1; };

__host__ __device__ constexpr uint32_t rotl32c(uint32_t x, int d) {
  return (x << d) | (x >> (32 - d));
}

__host__ __device__ constexpr TF2 threefry2x32(uint32_t k0, uint32_t k1,
                                               uint32_t c0, uint32_t c1) {
  const uint32_t ks2 = k0 ^ k1 ^ 0x1BD11BDAu;
  uint32_t x0 = c0 + k0;
  uint32_t x1 = c1 + k1;
  const int r0[4] = {13, 15, 26, 6};
  const int r1[4] = {17, 29, 16, 24};
  for (int i = 0; i < 4; i++) { x0 += x1; x1 = rotl32c(x1, r0[i]); x1 ^= x0; }
  x0 += k1;  x1 += ks2 + 1u;
  for (int i = 0; i < 4; i++) { x0 += x1; x1 = rotl32c(x1, r1[i]); x1 ^= x0; }
  x0 += ks2; x1 += k0 + 2u;
  for (int i = 0; i < 4; i++) { x0 += x1; x1 = rotl32c(x1, r0[i]); x1 ^= x0; }
  x0 += k0;  x1 += k1 + 3u;
  for (int i = 0; i < 4; i++) { x0 += x1; x1 = rotl32c(x1, r1[i]); x1 ^= x0; }
  x0 += k1;  x1 += ks2 + 4u;
  for (int i = 0; i < 4; i++) { x0 += x1; x1 = rotl32c(x1, r0[i]); x1 ^= x0; }
  x0 += ks2; x1 += k0 + 5u;
  return TF2{x0, x1};
}

// jax.random.key(42) -> (0, 42); dk1, dk2 = split(key) (fold-like)
constexpr TF2 DK1 = threefry2x32(0u, 42u, 0u, 0u);
constexpr TF2 DK2 = threefry2x32(0u, 42u, 0u, 1u);

__device__ __forceinline__ float drop_scale(uint32_t k0, uint32_t k1, uint32_t m) {
  TF2 r = threefry2x32(k0, k1, 0u, m);
  const uint32_t bits = r.x0 ^ r.x1;               // partitionable 32-bit bits
  float u = __uint_as_float((bits >> 9) | 0x3f800000u) - 1.0f;
  return (u < 0.9f) ? (1.0f / 0.9f) : 0.0f;        // keep-prob 0.9, scale 1/0.9
}

// ---------------------------------------------------------------------------
// Prep kernels: degree histogram, dinv_sqrt + CSR range-grab, CSR fill.
// CSR is UNSORTED per node (atomic slot grab) — fp32 sum order varies by
// ~1e-7, far under the 8.5e-4 threshold.
// ---------------------------------------------------------------------------
__global__ __launch_bounds__(256) void k_deg(const int* __restrict__ dst,
                                             unsigned* __restrict__ deg) {
  const int e = blockIdx.x * 256 + threadIdx.x;
  atomicAdd(&deg[dst[e]], 1u);
}

__global__ __launch_bounds__(256) void k_dinv(const unsigned* __restrict__ deg,
                                              float* __restrict__ dinv,
                                              unsigned* __restrict__ start,
                                              unsigned* __restrict__ counter) {
  const int n = blockIdx.x * 256 + threadIdx.x;
  if (n < NN) {
    const unsigned d = deg[n];
    dinv[n] = 1.0f / sqrtf((float)d + 1.0f);   // self-loop adds 1 to degree
    start[n] = atomicAdd(counter, d);          // disjoint ranges, order-free
  }
}

__global__ __launch_bounds__(256) void k_fill(const int* __restrict__ src,
                                              const int* __restrict__ dst,
                                              const unsigned* __restrict__ start,
                                              unsigned* __restrict__ fill,
                                              int* __restrict__ csr) {
  const int e = blockIdx.x * 256 + threadIdx.x;
  const int d = dst[e];
  const unsigned slot = atomicAdd(&fill[d], 1u);
  csr[start[d] + slot] = src[e];
}

// ---------------------------------------------------------------------------
// GEMM: H[N,128] = X[N,128] @ W[128,128], fp32 vector ALU.
// 32 rows/block, 4 rows/thread, W staged in LDS in two 64-row K-chunks
// (48 KB static LDS <= 64 KB cap). x-reads are subgroup-broadcast LDS.
// ---------------------------------------------------------------------------
__global__ __launch_bounds__(256) void k_gemm(const float* __restrict__ X,
                                              const float* __restrict__ W,
                                              float* __restrict__ H) {
  __shared__ float sX[32 * 128];   // 16 KB
  __shared__ float sW[64 * 128];   // 32 KB
  const int tid = threadIdx.x;
  const size_t rowBase = (size_t)blockIdx.x * 32;

  {
    const float4* Xg = (const float4*)(X + rowBase * 128);
    float4* sX4 = (float4*)sX;
#pragma unroll
    for (int i = 0; i < 4; i++) sX4[tid + i * 256] = Xg[tid + i * 256];
  }

  const int sub = tid >> 5;   // 0..7
  const int j4  = tid & 31;   // float4 column chunk
  float4 z = {0.f, 0.f, 0.f, 0.f};
  float4 acc0 = z, acc1 = z, acc2 = z, acc3 = z;

  for (int ph = 0; ph < 2; ph++) {
    __syncthreads();
    {
      const float4* Wg = (const float4*)(W + ph * 64 * 128);
      float4* sW4 = (float4*)sW;
#pragma unroll
      for (int i = 0; i < 8; i++) sW4[tid + i * 256] = Wg[tid + i * 256];
    }
    __syncthreads();
    const float* x0p = sX + (sub +  0) * 128 + ph * 64;
    const float* x1p = sX + (sub +  8) * 128 + ph * 64;
    const float* x2p = sX + (sub + 16) * 128 + ph * 64;
    const float* x3p = sX + (sub + 24) * 128 + ph * 64;
#pragma unroll 4
    for (int k = 0; k < 64; k++) {
      const float4 w = ((const float4*)sW)[k * 32 + j4];
      const float a0 = x0p[k], a1 = x1p[k], a2 = x2p[k], a3 = x3p[k];
      acc0.x = fmaf(a0, w.x, acc0.x); acc0.y = fmaf(a0, w.y, acc0.y);
      acc0.z = fmaf(a0, w.z, acc0.z); acc0.w = fmaf(a0, w.w, acc0.w);
      acc1.x = fmaf(a1, w.x, acc1.x); acc1.y = fmaf(a1, w.y, acc1.y);
      acc1.z = fmaf(a1, w.z, acc1.z); acc1.w = fmaf(a1, w.w, acc1.w);
      acc2.x = fmaf(a2, w.x, acc2.x); acc2.y = fmaf(a2, w.y, acc2.y);
      acc2.z = fmaf(a2, w.z, acc2.z); acc2.w = fmaf(a2, w.w, acc2.w);
      acc3.x = fmaf(a3, w.x, acc3.x); acc3.y = fmaf(a3, w.y, acc3.y);
      acc3.z = fmaf(a3, w.z, acc3.z); acc3.w = fmaf(a3, w.w, acc3.w);
    }
  }

  float4* Hg = (float4*)(H + rowBase * 128);
  Hg[(sub +  0) * 32 + j4] = acc0;
  Hg[(sub +  8) * 32 + j4] = acc1;
  Hg[(sub + 16) * 32 + j4] = acc2;
  Hg[(sub + 24) * 32 + j4] = acc3;
}

// ---------------------------------------------------------------------------
// Aggregation: one 32-lane subgroup per node, float4 per lane (128 feats).
// acc = dinv^2 * h[n] + sum_edges dinv[src]*dinv[n] * h[src]; then fused
// bias + leaky_relu + threefry dropout. LAYER==2 additionally fuses the
// out = z @ Wl + bl head via width-32 shuffle reduction. No atomics.
// Edge IDs + dinv[src] are gathered 32-wide then shuffle-broadcast, so the
// inner loop has no dependent scalar-load chain.
// ---------------------------------------------------------------------------
template <int LAYER>
__global__ __launch_bounds__(256) void k_agg(const float* __restrict__ H,
                                             const int* __restrict__ csr,
                                             const unsigned* __restrict__ start,
                                             const unsigned* __restrict__ degc,
                                             const float* __restrict__ dinv,
                                             const float* __restrict__ bias,
                                             const float* __restrict__ Wl,
                                             const float* __restrict__ bl,
                                             float* __restrict__ out) {
  const int tid  = threadIdx.x;
  const int lane = tid & 31;
  const int n    = blockIdx.x * 8 + (tid >> 5);   // 12500*8 == 100000 exactly

  const float di = dinv[n];
  const float4* __restrict__ H4 = (const float4*)H;

  float4 hv = H4[(size_t)n * 32 + lane];
  const float sw = di * di;
  float4 acc;
  acc.x = hv.x * sw; acc.y = hv.y * sw; acc.z = hv.z * sw; acc.w = hv.w * sw;

  const unsigned s   = start[n];
  const unsigned cnt = degc[n];
  for (unsigned base = 0; base < cnt; base += 32) {
    const unsigned rem = cnt - base;
    int srcl = 0; float dl = 0.0f;
    if (lane < (int)rem) { srcl = csr[s + base + lane]; dl = dinv[srcl]; }
    const int m = rem < 32u ? (int)rem : 32;
    for (int i = 0; i < m; i++) {
      const int src   = __shfl(srcl, i, 32);
      const float wgt = __shfl(dl, i, 32) * di;
      const float4 g  = H4[(size_t)src * 32 + lane];
      acc.x = fmaf(wgt, g.x, acc.x);
      acc.y = fmaf(wgt, g.y, acc.y);
      acc.z = fmaf(wgt, g.z, acc.z);
      acc.w = fmaf(wgt, g.w, acc.w);
    }
  }

  const float4 b = ((const float4*)bias)[lane];
  float v0 = acc.x + b.x, v1 = acc.y + b.y, v2 = acc.z + b.z, v3 = acc.w + b.w;
  v0 = v0 >= 0.f ? v0 : 0.01f * v0;
  v1 = v1 >= 0.f ? v1 : 0.01f * v1;
  v2 = v2 >= 0.f ? v2 : 0.01f * v2;
  v3 = v3 >= 0.f ? v3 : 0.01f * v3;

  const uint32_t k0 = (LAYER == 1) ? DK1.x0 : DK2.x0;
  const uint32_t k1 = (LAYER == 1) ? DK1.x1 : DK2.x1;
  const uint32_t mb = (uint32_t)n * 128u + (uint32_t)lane * 4u;
  v0 *= drop_scale(k0, k1, mb + 0u);
  v1 *= drop_scale(k0, k1, mb + 1u);
  v2 *= drop_scale(k0, k1, mb + 2u);
  v3 *= drop_scale(k0, k1, mb + 3u);

  if constexpr (LAYER == 1) {
    float4 o; o.x = v0; o.y = v1; o.z = v2; o.w = v3;
    ((float4*)out)[(size_t)n * 32 + lane] = o;
  } else {
    const float4 wl = ((const float4*)Wl)[lane];
    float p = v0 * wl.x + v1 * wl.y + v2 * wl.z + v3 * wl.w;
#pragma unroll
    for (int d = 16; d > 0; d >>= 1) p += __shfl_down(p, d, 32);
    if (lane == 0) out[n] = p + bl[0];
  }
}

// ---------------------------------------------------------------------------
extern "C" void kernel_launch(void* const* d_in, const int* in_sizes, int n_in,
                              void* d_out, int out_size, void* d_ws, size_t ws_size,
                              hipStream_t stream) {
  const float* x  = (const float*)d_in[0];
  const int*   ei = (const int*)d_in[1];    // [2, E] int32; row0=src, row1=dst
  const float* W1 = (const float*)d_in[2];
  const float* b1 = (const float*)d_in[3];
  const float* W2 = (const float*)d_in[4];
  const float* b2 = (const float*)d_in[5];
  const float* Wl = (const float*)d_in[6];
  const float* bl = (const float*)d_in[7];
  float* out = (float*)d_out;

  // workspace layout (~110.4 MB total)
  unsigned* deg     = (unsigned*)d_ws;            // 100000 u32
  unsigned* fill    = deg + NN;                   // 100000 u32
  unsigned* counter = fill + NN;                  // 8 u32 (1 used + pad)
  unsigned* start   = counter + 8;                // 100000 u32
  float*    dinv    = (float*)(start + NN);       // 100000 f32
  int*      csr     = (int*)(dinv + NN);          // 1.6M i32
  float*    bufA    = (float*)(csr + EE);         // 12.8M f32 (16B-aligned)
  float*    bufB    = bufA + (size_t)NN * FD;     // 12.8M f32

  const int* srcI = ei;
  const int* dstI = ei + EE;

  // zero deg + fill + counter (contiguous region)
  hipMemsetAsync(deg, 0, (size_t)(2 * NN + 8) * sizeof(unsigned), stream);

  k_deg <<<EE / 256, 256, 0, stream>>>(dstI, deg);
  k_dinv<<<(NN + 255) / 256, 256, 0, stream>>>(deg, dinv, start, counter);
  k_fill<<<EE / 256, 256, 0, stream>>>(srcI, dstI, start, fill, csr);

  k_gemm<<<NN / 32, 256, 0, stream>>>(x, W1, bufA);                 // h1
  k_agg<1><<<NN / 8, 256, 0, stream>>>(bufA, csr, start, deg, dinv,
                                       b1, nullptr, nullptr, bufB); // y1
  k_gemm<<<NN / 32, 256, 0, stream>>>(bufB, W2, bufA);              // h2
  k_agg<2><<<NN / 8, 256, 0, stream>>>(bufA, csr, start, deg, dinv,
                                       b2, Wl, bl, out);            // out
}